// Round 9
// baseline (469.643 us; speedup 1.0000x reference)
//
#include <hip/hip_runtime.h>

#define N_NODES 100000
#define E_EDGES 1600000
#define CIN 64
#define CHID 128
#define COUT 64
#define NT 64                         // nodes per GEMM block
#define NB ((N_NODES + NT - 1) / NT)  // 1563
#define RBLK 64                       // slab blocks for stat reduce
#define CAP 128                       // bucket capacity per node (max degree << CAP)

__device__ __forceinline__ void fma4(float4& c, float s, const float4& w) {
    c.x = fmaf(s, w.x, c.x); c.y = fmaf(s, w.y, c.y);
    c.z = fmaf(s, w.z, c.z); c.w = fmaf(s, w.w, c.w);
}

// ---------------- bucket scatter: counting-sort-free CSR --------------------
__global__ void bucket_kernel(const int* __restrict__ ei, int* __restrict__ cnt,
                              int2* __restrict__ es) {
    int e = blockIdx.x * blockDim.x + threadIdx.x;
    if (e < E_EDGES) {
        int src = ei[e];
        int dst = ei[E_EDGES + e];
        int p = atomicAdd(&cnt[dst], 1);
        if (p < CAP) es[((long)dst << 7) + p] = make_int2(e, src);
    }
}

// ---------------- gather: softmax-aggregate per node, fuse root add --------
// aggr = sum(msg*exp(msg)) / (sum(exp(msg)) + 1e-16); exp(max) cancels vs ref.
// Round-7 proven form: lane = channel, 8-deep unroll -> 16 rows in flight.
__global__ void gather_kernel(const float* __restrict__ x,
                              const float* __restrict__ ea,
                              const int2* __restrict__ es,
                              const int* __restrict__ cnt,
                              float* __restrict__ h0) {
    int node = (blockIdx.x * blockDim.x + threadIdx.x) >> 6;
    int lane = threadIdx.x & 63;
    if (node >= N_NODES) return;
    long s = (long)node << 7;
    int n = cnt[node];
    n = n > CAP ? CAP : n;
    float nm = 0.f, dn = 0.f;
    int p = 0;
    for (; p + 8 <= n; p += 8) {
        int2 q[8];
#pragma unroll
        for (int u = 0; u < 8; ++u) q[u] = es[s + p + u];
        float av[8], xv[8];
#pragma unroll
        for (int u = 0; u < 8; ++u) av[u] = ea[(long)q[u].x * CIN + lane];
#pragma unroll
        for (int u = 0; u < 8; ++u) xv[u] = x[(long)q[u].y * CIN + lane];
#pragma unroll
        for (int u = 0; u < 8; ++u) {
            float m = fmaxf(xv[u] + av[u], 0.f) + 1e-7f;
            float ex = __expf(m);
            nm = fmaf(m, ex, nm);
            dn += ex;
        }
    }
    for (; p + 4 <= n; p += 4) {
        int2 q[4];
#pragma unroll
        for (int u = 0; u < 4; ++u) q[u] = es[s + p + u];
        float av[4], xv[4];
#pragma unroll
        for (int u = 0; u < 4; ++u) av[u] = ea[(long)q[u].x * CIN + lane];
#pragma unroll
        for (int u = 0; u < 4; ++u) xv[u] = x[(long)q[u].y * CIN + lane];
#pragma unroll
        for (int u = 0; u < 4; ++u) {
            float m = fmaxf(xv[u] + av[u], 0.f) + 1e-7f;
            float ex = __expf(m);
            nm = fmaf(m, ex, nm);
            dn += ex;
        }
    }
    for (; p < n; ++p) {
        int2 q = es[s + p];
        float m = fmaxf(x[(long)q.y * CIN + lane] + ea[(long)q.x * CIN + lane], 0.f) + 1e-7f;
        float ex = __expf(m);
        nm = fmaf(m, ex, nm);
        dn += ex;
    }
    h0[(long)node * CIN + lane] = nm / (dn + 1e-16f) + x[(long)node * CIN + lane];
}

// ---------------- slab reduce with last-block-fused finalize ----------------
__global__ void reduce_slab_kernel(const float* __restrict__ P, int totrows,
                                   int rows_per, float* __restrict__ Q,
                                   float* __restrict__ mr, int C, float invN,
                                   int* __restrict__ ticket) {
    int C2 = blockDim.x;
    int t = threadIdx.x;
    long r0 = (long)blockIdx.x * rows_per;
    long r1 = r0 + rows_per;
    if (r1 > totrows) r1 = totrows;
    {
        float s0 = 0.f, s1 = 0.f, s2 = 0.f, s3 = 0.f;
        long r = r0;
        for (; r + 4 <= r1; r += 4) {
            s0 += P[(r + 0) * C2 + t];
            s1 += P[(r + 1) * C2 + t];
            s2 += P[(r + 2) * C2 + t];
            s3 += P[(r + 3) * C2 + t];
        }
        for (; r < r1; ++r) s0 += P[r * C2 + t];
        Q[(long)blockIdx.x * C2 + t] = (s0 + s1) + (s2 + s3);
    }
    __threadfence();
    __shared__ int lastFlag;
    if (t == 0) lastFlag = (atomicAdd(ticket, 1) == (int)gridDim.x - 1);
    __syncthreads();
    if (!lastFlag) return;
    __threadfence();
    float s0 = 0.f, s1 = 0.f, s2 = 0.f, s3 = 0.f;
    for (int r = 0; r < RBLK; r += 4) {
        s0 += Q[(long)(r + 0) * C2 + t];
        s1 += Q[(long)(r + 1) * C2 + t];
        s2 += Q[(long)(r + 2) * C2 + t];
        s3 += Q[(long)(r + 3) * C2 + t];
    }
    __shared__ float sm[256];
    sm[t] = (s0 + s1) + (s2 + s3);
    __syncthreads();
    if (t < C) {
        float m = sm[t] * invN;
        float v = sm[C + t] * invN - m * m;
        mr[t] = m;
        mr[C + t] = rsqrtf(fmaxf(v, 0.f) + 1e-5f);
    }
}

// ---------------- GEMM1: t1 = h0 @ W1 + b1, partial BN1 sums ----------------
__global__ void __launch_bounds__(256) gemm1_kernel(
        const float* __restrict__ h0, const float* __restrict__ W1,
        const float* __restrict__ b1, float* __restrict__ t1,
        float* __restrict__ P) {
    __shared__ float sW[CIN * CHID];  // 32 KiB
    __shared__ float sh[NT * CIN];    // 16 KiB
    int tid = threadIdx.x;
    int nbase = blockIdx.x * NT;
    for (int i = tid * 4; i < CIN * CHID; i += 1024)
        *(float4*)&sW[i] = *(const float4*)&W1[i];
    for (int i = tid * 4; i < NT * CIN; i += 1024) {
        int node = nbase + (i >> 6);
        float4 v = make_float4(0.f, 0.f, 0.f, 0.f);
        if (node < N_NODES) v = *(const float4*)&h0[(long)node * CIN + (i & 63)];
        *(float4*)&sh[i] = v;
    }
    __syncthreads();
    int js = (tid & 31) * 4;  // out channels js..js+3
    int r  = tid >> 5;        // node group, nodes r*8 .. r*8+7
    float4 bb = *(const float4*)&b1[js];
    float4 acc[8];
#pragma unroll
    for (int i = 0; i < 8; ++i) acc[i] = bb;
    for (int k = 0; k < CIN; k += 4) {
        float4 w0 = *(float4*)&sW[(k + 0) * CHID + js];
        float4 w1 = *(float4*)&sW[(k + 1) * CHID + js];
        float4 w2 = *(float4*)&sW[(k + 2) * CHID + js];
        float4 w3 = *(float4*)&sW[(k + 3) * CHID + js];
#pragma unroll
        for (int i = 0; i < 8; ++i) {
            float4 a = *(float4*)&sh[(r * 8 + i) * CIN + k];
            fma4(acc[i], a.x, w0);
            fma4(acc[i], a.y, w1);
            fma4(acc[i], a.z, w2);
            fma4(acc[i], a.w, w3);
        }
    }
    float4 s1 = make_float4(0.f, 0.f, 0.f, 0.f);
    float4 s2 = make_float4(0.f, 0.f, 0.f, 0.f);
#pragma unroll
    for (int i = 0; i < 8; ++i) {
        int node = nbase + r * 8 + i;
        if (node < N_NODES) {
            *(float4*)&t1[(long)node * CHID + js] = acc[i];
            s1.x += acc[i].x; s1.y += acc[i].y; s1.z += acc[i].z; s1.w += acc[i].w;
            s2.x = fmaf(acc[i].x, acc[i].x, s2.x);
            s2.y = fmaf(acc[i].y, acc[i].y, s2.y);
            s2.z = fmaf(acc[i].z, acc[i].z, s2.z);
            s2.w = fmaf(acc[i].w, acc[i].w, s2.w);
        }
    }
    float* p = P + (long)blockIdx.x * 2048 + r * 256;  // 8 rows x 256
    *(float4*)&p[js]       = s1;
    *(float4*)&p[128 + js] = s2;
}

// ---------------- GEMM2: h2 = relu(BN1(t1)) @ W2 + b2, partial BN2 sums -----
__global__ void __launch_bounds__(256) gemm2_kernel(
        const float* __restrict__ t1, const float* __restrict__ mr1,
        const float* __restrict__ g, const float* __restrict__ be,
        const float* __restrict__ W2, const float* __restrict__ b2,
        float* __restrict__ h2, float* __restrict__ P) {
    __shared__ float sW[CHID * COUT]; // 32 KiB
    __shared__ float sr[NT * CHID];   // 32 KiB
    int tid = threadIdx.x;
    int nbase = blockIdx.x * NT;
    for (int i = tid * 4; i < CHID * COUT; i += 1024)
        *(float4*)&sW[i] = *(const float4*)&W2[i];
    for (int i = tid * 4; i < NT * CHID; i += 1024) {
        int node = nbase + (i >> 7);
        int j = i & 127;
        float4 v = make_float4(0.f, 0.f, 0.f, 0.f);
        if (node < N_NODES) {
            v = *(const float4*)&t1[(long)node * CHID + j];
            float4 mn = *(const float4*)&mr1[j];
            float4 rq = *(const float4*)&mr1[CHID + j];
            float4 gg = *(const float4*)&g[j];
            float4 bb = *(const float4*)&be[j];
            v.x = fmaxf((v.x - mn.x) * rq.x * gg.x + bb.x, 0.f);
            v.y = fmaxf((v.y - mn.y) * rq.y * gg.y + bb.y, 0.f);
            v.z = fmaxf((v.z - mn.z) * rq.z * gg.z + bb.z, 0.f);
            v.w = fmaxf((v.w - mn.w) * rq.w * gg.w + bb.w, 0.f);
        }
        *(float4*)&sr[i] = v;
    }
    __syncthreads();
    int js = (tid & 15) * 4;  // out channels
    int r  = tid >> 4;        // node group, nodes r*4 .. r*4+3
    float4 bb = *(const float4*)&b2[js];
    float4 acc[4];
#pragma unroll
    for (int i = 0; i < 4; ++i) acc[i] = bb;
    for (int k = 0; k < CHID; k += 4) {
        float4 w0 = *(float4*)&sW[(k + 0) * COUT + js];
        float4 w1 = *(float4*)&sW[(k + 1) * COUT + js];
        float4 w2 = *(float4*)&sW[(k + 2) * COUT + js];
        float4 w3 = *(float4*)&sW[(k + 3) * COUT + js];
#pragma unroll
        for (int i = 0; i < 4; ++i) {
            float4 a = *(float4*)&sr[(r * 4 + i) * CHID + k];
            fma4(acc[i], a.x, w0);
            fma4(acc[i], a.y, w1);
            fma4(acc[i], a.z, w2);
            fma4(acc[i], a.w, w3);
        }
    }
    float4 s1 = make_float4(0.f, 0.f, 0.f, 0.f);
    float4 s2 = make_float4(0.f, 0.f, 0.f, 0.f);
#pragma unroll
    for (int i = 0; i < 4; ++i) {
        int node = nbase + r * 4 + i;
        if (node < N_NODES) {
            *(float4*)&h2[(long)node * COUT + js] = acc[i];
            s1.x += acc[i].x; s1.y += acc[i].y; s1.z += acc[i].z; s1.w += acc[i].w;
            s2.x = fmaf(acc[i].x, acc[i].x, s2.x);
            s2.y = fmaf(acc[i].y, acc[i].y, s2.y);
            s2.z = fmaf(acc[i].z, acc[i].z, s2.z);
            s2.w = fmaf(acc[i].w, acc[i].w, s2.w);
        }
    }
    float* p = P + (long)blockIdx.x * 2048 + r * 128;  // 16 rows x 128
    *(float4*)&p[js]      = s1;
    *(float4*)&p[64 + js] = s2;
}

// ---------------- GEMM3: t3 = silu(BN2(h2)) @ Wl, partial BN3 sums ----------
__global__ void __launch_bounds__(256) gemm3_kernel(
        const float* __restrict__ h2, const float* __restrict__ mr2,
        const float* __restrict__ g, const float* __restrict__ be,
        const float* __restrict__ Wl,
        float* __restrict__ t3, float* __restrict__ P) {
    __shared__ float sW[COUT * COUT]; // 16 KiB
    __shared__ float sr[NT * COUT];   // 16 KiB
    int tid = threadIdx.x;
    int nbase = blockIdx.x * NT;
    for (int i = tid * 4; i < COUT * COUT; i += 1024)
        *(float4*)&sW[i] = *(const float4*)&Wl[i];
    for (int i = tid * 4; i < NT * COUT; i += 1024) {
        int node = nbase + (i >> 6);
        int j = i & 63;
        float4 v = make_float4(0.f, 0.f, 0.f, 0.f);
        if (node < N_NODES) {
            v = *(const float4*)&h2[(long)node * COUT + j];
            float4 mn = *(const float4*)&mr2[j];
            float4 rq = *(const float4*)&mr2[COUT + j];
            float4 gg = *(const float4*)&g[j];
            float4 bb = *(const float4*)&be[j];
            v.x = (v.x - mn.x) * rq.x * gg.x + bb.x;
            v.y = (v.y - mn.y) * rq.y * gg.y + bb.y;
            v.z = (v.z - mn.z) * rq.z * gg.z + bb.z;
            v.w = (v.w - mn.w) * rq.w * gg.w + bb.w;
            v.x = v.x / (1.f + __expf(-v.x));
            v.y = v.y / (1.f + __expf(-v.y));
            v.z = v.z / (1.f + __expf(-v.z));
            v.w = v.w / (1.f + __expf(-v.w));
        }
        *(float4*)&sr[i] = v;
    }
    __syncthreads();
    int js = (tid & 15) * 4;
    int r  = tid >> 4;
    float4 acc[4];
#pragma unroll
    for (int i = 0; i < 4; ++i) acc[i] = make_float4(0.f, 0.f, 0.f, 0.f);
    for (int k = 0; k < COUT; k += 4) {
        float4 w0 = *(float4*)&sW[(k + 0) * COUT + js];
        float4 w1 = *(float4*)&sW[(k + 1) * COUT + js];
        float4 w2 = *(float4*)&sW[(k + 2) * COUT + js];
        float4 w3 = *(float4*)&sW[(k + 3) * COUT + js];
#pragma unroll
        for (int i = 0; i < 4; ++i) {
            float4 a = *(float4*)&sr[(r * 4 + i) * COUT + k];
            fma4(acc[i], a.x, w0);
            fma4(acc[i], a.y, w1);
            fma4(acc[i], a.z, w2);
            fma4(acc[i], a.w, w3);
        }
    }
    float4 s1 = make_float4(0.f, 0.f, 0.f, 0.f);
    float4 s2 = make_float4(0.f, 0.f, 0.f, 0.f);
#pragma unroll
    for (int i = 0; i < 4; ++i) {
        int node = nbase + r * 4 + i;
        if (node < N_NODES) {
            *(float4*)&t3[(long)node * COUT + js] = acc[i];
            s1.x += acc[i].x; s1.y += acc[i].y; s1.z += acc[i].z; s1.w += acc[i].w;
            s2.x = fmaf(acc[i].x, acc[i].x, s2.x);
            s2.y = fmaf(acc[i].y, acc[i].y, s2.y);
            s2.z = fmaf(acc[i].z, acc[i].z, s2.z);
            s2.w = fmaf(acc[i].w, acc[i].w, s2.w);
        }
    }
    float* p = P + (long)blockIdx.x * 2048 + r * 128;
    *(float4*)&p[js]      = s1;
    *(float4*)&p[64 + js] = s2;
}

// ---------------- final: out = silu(BN3(t3)), float4 ------------------------
__global__ void final_kernel(const float* __restrict__ t3, const float* __restrict__ mr3,
                             const float* __restrict__ g, const float* __restrict__ be,
                             float* __restrict__ out) {
    long i = ((long)blockIdx.x * blockDim.x + threadIdx.x) * 4;
    int j = (int)(i & 63);
    float4 v = *(const float4*)&t3[i];
    float4 mn = *(const float4*)&mr3[j];
    float4 rq = *(const float4*)&mr3[COUT + j];
    float4 gg = *(const float4*)&g[j];
    float4 bb = *(const float4*)&be[j];
    v.x = (v.x - mn.x) * rq.x * gg.x + bb.x;
    v.y = (v.y - mn.y) * rq.y * gg.y + bb.y;
    v.z = (v.z - mn.z) * rq.z * gg.z + bb.z;
    v.w = (v.w - mn.w) * rq.w * gg.w + bb.w;
    v.x = v.x / (1.f + __expf(-v.x));
    v.y = v.y / (1.f + __expf(-v.y));
    v.z = v.z / (1.f + __expf(-v.z));
    v.w = v.w / (1.f + __expf(-v.w));
    *(float4*)&out[i] = v;
}

extern "C" void kernel_launch(void* const* d_in, const int* in_sizes, int n_in,
                              void* d_out, int out_size, void* d_ws, size_t ws_size,
                              hipStream_t stream) {
    const float* x   = (const float*)d_in[0];
    const int*   ei  = (const int*)d_in[1];
    const float* ea  = (const float*)d_in[2];
    const float* W1  = (const float*)d_in[4];
    const float* b1  = (const float*)d_in[5];
    const float* gm  = (const float*)d_in[6];
    const float* bm  = (const float*)d_in[7];
    const float* W2  = (const float*)d_in[8];
    const float* b2  = (const float*)d_in[9];
    const float* g1  = (const float*)d_in[10];
    const float* be1 = (const float*)d_in[11];
    const float* Wl  = (const float*)d_in[12];
    const float* g2  = (const float*)d_in[13];
    const float* be2 = (const float*)d_in[14];
    float* out = (float*)d_out;

    // workspace layout (floats):
    //   h0[N*64] | t1[N*128] | h2[N*64] | Sfin[512] | Q[16384] | cnt[N] |
    //   tickets[4] | pad | es[N*CAP int2]
    // stat partials alias dead regions: P1->h2, P2->h0, P3->t1
    float* h0   = (float*)d_ws;
    float* t1   = h0 + (long)N_NODES * CIN;
    float* h2   = t1 + (long)N_NODES * CHID;
    float* t3   = h0;
    float* Sfin = h2 + (long)N_NODES * COUT;
    float* Q    = Sfin + 512;
    int*   cnt  = (int*)(Q + RBLK * 256);
    int*   tickets = cnt + N_NODES;
    long   es_off = ((long)(N_NODES * CIN) + (long)N_NODES * CHID + (long)N_NODES * COUT
                     + 512 + RBLK * 256 + N_NODES + 4 + 255) & ~255L;
    int2*  es   = (int2*)((float*)d_ws + es_off);
    float* P1 = h2;
    float* P2 = h0;
    float* P3 = t1;

    const float invN = 1.f / N_NODES;

    hipMemsetAsync(cnt, 0, ((size_t)N_NODES + 4) * sizeof(int), stream);

    bucket_kernel<<<(E_EDGES + 255) / 256, 256, 0, stream>>>(ei, cnt, es);
    gather_kernel<<<(N_NODES * 64 + 255) / 256, 256, 0, stream>>>(x, ea, es, cnt, h0);

    const int tot1 = NB * 8,  rp1 = (tot1 + RBLK - 1) / RBLK;   // 12504, 196
    const int tot2 = NB * 16, rp2 = (tot2 + RBLK - 1) / RBLK;   // 25008, 391

    gemm1_kernel<<<NB, 256, 0, stream>>>(h0, W1, b1, t1, P1);
    reduce_slab_kernel<<<RBLK, 256, 0, stream>>>(P1, tot1, rp1, Q, Sfin, CHID, invN, tickets + 0);
    gemm2_kernel<<<NB, 256, 0, stream>>>(t1, Sfin, gm, bm, W2, b2, h2, P2);
    reduce_slab_kernel<<<RBLK, 128, 0, stream>>>(P2, tot2, rp2, Q, Sfin + 256, COUT, invN, tickets + 1);
    gemm3_kernel<<<NB, 256, 0, stream>>>(h2, Sfin + 256, g1, be1, Wl, t3, P3);
    reduce_slab_kernel<<<RBLK, 128, 0, stream>>>(P3, tot2, rp2, Q, Sfin + 384, COUT, invN, tickets + 2);
    final_kernel<<<(N_NODES * COUT / 4) / 256, 256, 0, stream>>>(t3, Sfin + 384, g2, be2, out);
}

// Round 10
// 380.736 us; speedup vs baseline: 1.2335x; 1.2335x over previous
//
#include <hip/hip_runtime.h>

#define N_NODES 100000
#define E_EDGES 1600000
#define CIN 64
#define CHID 128
#define COUT 64
#define NT 64                         // nodes per GEMM block
#define NB ((N_NODES + NT - 1) / NT)  // 1563
#define RBLK 64                       // slab blocks for stat reduce
#define CAP 128                       // bucket capacity per node (max degree << CAP)

// ---------------- bucket scatter: counting-sort-free CSR --------------------
__global__ void bucket_kernel(const int* __restrict__ ei, int* __restrict__ cnt,
                              int2* __restrict__ es) {
    int e = blockIdx.x * blockDim.x + threadIdx.x;
    if (e < E_EDGES) {
        int src = ei[e];
        int dst = ei[E_EDGES + e];
        int p = atomicAdd(&cnt[dst], 1);
        if (p < CAP) es[((long)dst << 7) + p] = make_int2(e, src);
    }
}

// ---------------- gather: softmax-aggregate per node, fuse root add --------
// aggr = sum(msg*exp(msg)) / (sum(exp(msg)) + 1e-16); exp(max) cancels vs ref.
// Round-7 proven form: lane = channel, 8-deep unroll -> 16 rows in flight.
__global__ void gather_kernel(const float* __restrict__ x,
                              const float* __restrict__ ea,
                              const int2* __restrict__ es,
                              const int* __restrict__ cnt,
                              float* __restrict__ h0) {
    int node = (blockIdx.x * blockDim.x + threadIdx.x) >> 6;
    int lane = threadIdx.x & 63;
    if (node >= N_NODES) return;
    long s = (long)node << 7;
    int n = cnt[node];
    n = n > CAP ? CAP : n;
    float nm = 0.f, dn = 0.f;
    int p = 0;
    for (; p + 8 <= n; p += 8) {
        int2 q[8];
#pragma unroll
        for (int u = 0; u < 8; ++u) q[u] = es[s + p + u];
        float av[8], xv[8];
#pragma unroll
        for (int u = 0; u < 8; ++u) av[u] = ea[(long)q[u].x * CIN + lane];
#pragma unroll
        for (int u = 0; u < 8; ++u) xv[u] = x[(long)q[u].y * CIN + lane];
#pragma unroll
        for (int u = 0; u < 8; ++u) {
            float m = fmaxf(xv[u] + av[u], 0.f) + 1e-7f;
            float ex = __expf(m);
            nm = fmaf(m, ex, nm);
            dn += ex;
        }
    }
    for (; p + 4 <= n; p += 4) {
        int2 q[4];
#pragma unroll
        for (int u = 0; u < 4; ++u) q[u] = es[s + p + u];
        float av[4], xv[4];
#pragma unroll
        for (int u = 0; u < 4; ++u) av[u] = ea[(long)q[u].x * CIN + lane];
#pragma unroll
        for (int u = 0; u < 4; ++u) xv[u] = x[(long)q[u].y * CIN + lane];
#pragma unroll
        for (int u = 0; u < 4; ++u) {
            float m = fmaxf(xv[u] + av[u], 0.f) + 1e-7f;
            float ex = __expf(m);
            nm = fmaf(m, ex, nm);
            dn += ex;
        }
    }
    for (; p < n; ++p) {
        int2 q = es[s + p];
        float m = fmaxf(x[(long)q.y * CIN + lane] + ea[(long)q.x * CIN + lane], 0.f) + 1e-7f;
        float ex = __expf(m);
        nm = fmaf(m, ex, nm);
        dn += ex;
    }
    h0[(long)node * CIN + lane] = nm / (dn + 1e-16f) + x[(long)node * CIN + lane];
}

// ---------------- slab reduce with last-block-fused finalize ----------------
// P is now ONE row per GEMM block (in-block pre-reduced).
__global__ void reduce_slab_kernel(const float* __restrict__ P, int totrows,
                                   int rows_per, float* __restrict__ Q,
                                   float* __restrict__ mr, int C, float invN,
                                   int* __restrict__ ticket) {
    int C2 = blockDim.x;
    int t = threadIdx.x;
    long r0 = (long)blockIdx.x * rows_per;
    long r1 = r0 + rows_per;
    if (r1 > totrows) r1 = totrows;
    {
        float s0 = 0.f, s1 = 0.f, s2 = 0.f, s3 = 0.f;
        long r = r0;
        for (; r + 4 <= r1; r += 4) {
            s0 += P[(r + 0) * C2 + t];
            s1 += P[(r + 1) * C2 + t];
            s2 += P[(r + 2) * C2 + t];
            s3 += P[(r + 3) * C2 + t];
        }
        for (; r < r1; ++r) s0 += P[r * C2 + t];
        Q[(long)blockIdx.x * C2 + t] = (s0 + s1) + (s2 + s3);
    }
    __threadfence();
    __shared__ int lastFlag;
    if (t == 0) lastFlag = (atomicAdd(ticket, 1) == (int)gridDim.x - 1);
    __syncthreads();
    if (!lastFlag) return;
    __threadfence();
    float s0 = 0.f, s1 = 0.f, s2 = 0.f, s3 = 0.f;
    for (int r = 0; r < RBLK; r += 4) {
        s0 += Q[(long)(r + 0) * C2 + t];
        s1 += Q[(long)(r + 1) * C2 + t];
        s2 += Q[(long)(r + 2) * C2 + t];
        s3 += Q[(long)(r + 3) * C2 + t];
    }
    __shared__ float sm[256];
    sm[t] = (s0 + s1) + (s2 + s3);
    __syncthreads();
    if (t < C) {
        float m = sm[t] * invN;
        float v = sm[C + t] * invN - m * m;
        mr[t] = m;
        mr[C + t] = rsqrtf(fmaxf(v, 0.f) + 1e-5f);
    }
}

// ---------------- GEMM1: t1 = h0 @ W1 + b1, in-block BN1 partial row --------
__global__ void __launch_bounds__(256) gemm1_kernel(
        const float* __restrict__ h0, const float* __restrict__ W1,
        const float* __restrict__ b1, float* __restrict__ t1,
        float* __restrict__ P) {
    __shared__ float sW[CIN * CHID];  // 32 KiB (reused as stat scratch)
    __shared__ float sh[NT * CIN];    // 16 KiB
    int tid = threadIdx.x;
    int nbase = blockIdx.x * NT;
    for (int i = tid * 4; i < CIN * CHID; i += 1024)
        *(float4*)&sW[i] = *(const float4*)&W1[i];
    for (int i = tid * 4; i < NT * CIN; i += 1024) {
        int node = nbase + (i >> 6);
        float4 v = make_float4(0.f, 0.f, 0.f, 0.f);
        if (node < N_NODES) v = *(const float4*)&h0[(long)node * CIN + (i & 63)];
        *(float4*)&sh[i] = v;
    }
    __syncthreads();
    int js = (tid & 31) * 4;  // out channels js..js+3
    int r  = tid >> 5;        // node group, nodes r*8 .. r*8+7
    float4 bb = *(const float4*)&b1[js];
    float acc[8][4];
#pragma unroll
    for (int i = 0; i < 8; ++i) { acc[i][0]=bb.x; acc[i][1]=bb.y; acc[i][2]=bb.z; acc[i][3]=bb.w; }
#pragma unroll 4
    for (int k = 0; k < CIN; ++k) {
        float4 w = *(float4*)&sW[k * CHID + js];
#pragma unroll
        for (int i = 0; i < 8; ++i) {
            float a = sh[(r * 8 + i) * CIN + k];
            acc[i][0] = fmaf(a, w.x, acc[i][0]);
            acc[i][1] = fmaf(a, w.y, acc[i][1]);
            acc[i][2] = fmaf(a, w.z, acc[i][2]);
            acc[i][3] = fmaf(a, w.w, acc[i][3]);
        }
    }
    float s1[4] = {0,0,0,0}, s2[4] = {0,0,0,0};
#pragma unroll
    for (int i = 0; i < 8; ++i) {
        int node = nbase + r * 8 + i;
        if (node < N_NODES) {
            *(float4*)&t1[(long)node * CHID + js] =
                make_float4(acc[i][0], acc[i][1], acc[i][2], acc[i][3]);
#pragma unroll
            for (int jj = 0; jj < 4; ++jj) {
                s1[jj] += acc[i][jj];
                s2[jj] += acc[i][jj] * acc[i][jj];
            }
        }
    }
    // in-block stat reduction: 8 r-groups -> one row of 256 (128 s1 | 128 s2)
    __syncthreads();                 // all sW reads done; safe to reuse
    float* red = sW;                 // [8][128] s1, then [8][128] s2
    *(float4*)&red[r * 128 + js]        = make_float4(s1[0], s1[1], s1[2], s1[3]);
    *(float4*)&red[1024 + r * 128 + js] = make_float4(s2[0], s2[1], s2[2], s2[3]);
    __syncthreads();
    {
        int base = (tid < 128) ? tid : (1024 + tid - 128);
        float v = 0.f;
#pragma unroll
        for (int rr = 0; rr < 8; ++rr) v += red[base + rr * 128];
        P[(long)blockIdx.x * 256 + tid] = v;
    }
}

// ---------------- GEMM2: h2 = relu(BN1(t1)) @ W2 + b2, in-block BN2 row -----
__global__ void __launch_bounds__(256) gemm2_kernel(
        const float* __restrict__ t1, const float* __restrict__ mr1,
        const float* __restrict__ g, const float* __restrict__ be,
        const float* __restrict__ W2, const float* __restrict__ b2,
        float* __restrict__ h2, float* __restrict__ P) {
    __shared__ float sW[CHID * COUT]; // 32 KiB (reused as stat scratch)
    __shared__ float sr[NT * CHID];   // 32 KiB
    int tid = threadIdx.x;
    int nbase = blockIdx.x * NT;
    for (int i = tid * 4; i < CHID * COUT; i += 1024)
        *(float4*)&sW[i] = *(const float4*)&W2[i];
    for (int i = tid * 4; i < NT * CHID; i += 1024) {
        int node = nbase + (i >> 7);
        int j = i & 127;
        float4 v = make_float4(0.f, 0.f, 0.f, 0.f);
        if (node < N_NODES) {
            v = *(const float4*)&t1[(long)node * CHID + j];
            float4 mn = *(const float4*)&mr1[j];
            float4 rq = *(const float4*)&mr1[CHID + j];
            float4 gg = *(const float4*)&g[j];
            float4 bb = *(const float4*)&be[j];
            v.x = fmaxf((v.x - mn.x) * rq.x * gg.x + bb.x, 0.f);
            v.y = fmaxf((v.y - mn.y) * rq.y * gg.y + bb.y, 0.f);
            v.z = fmaxf((v.z - mn.z) * rq.z * gg.z + bb.z, 0.f);
            v.w = fmaxf((v.w - mn.w) * rq.w * gg.w + bb.w, 0.f);
        }
        *(float4*)&sr[i] = v;
    }
    __syncthreads();
    int js = (tid & 15) * 4;  // out channels
    int r  = tid >> 4;        // node group, nodes r*4 .. r*4+3
    float4 bb = *(const float4*)&b2[js];
    float acc[4][4];
#pragma unroll
    for (int i = 0; i < 4; ++i) { acc[i][0]=bb.x; acc[i][1]=bb.y; acc[i][2]=bb.z; acc[i][3]=bb.w; }
#pragma unroll 4
    for (int k = 0; k < CHID; ++k) {
        float4 w = *(float4*)&sW[k * COUT + js];
#pragma unroll
        for (int i = 0; i < 4; ++i) {
            float a = sr[(r * 4 + i) * CHID + k];
            acc[i][0] = fmaf(a, w.x, acc[i][0]);
            acc[i][1] = fmaf(a, w.y, acc[i][1]);
            acc[i][2] = fmaf(a, w.z, acc[i][2]);
            acc[i][3] = fmaf(a, w.w, acc[i][3]);
        }
    }
    float s1[4] = {0,0,0,0}, s2[4] = {0,0,0,0};
#pragma unroll
    for (int i = 0; i < 4; ++i) {
        int node = nbase + r * 4 + i;
        if (node < N_NODES) {
            *(float4*)&h2[(long)node * COUT + js] =
                make_float4(acc[i][0], acc[i][1], acc[i][2], acc[i][3]);
#pragma unroll
            for (int jj = 0; jj < 4; ++jj) {
                s1[jj] += acc[i][jj];
                s2[jj] += acc[i][jj] * acc[i][jj];
            }
        }
    }
    // in-block stat reduction: 16 r-groups -> one row of 128 (64 s1 | 64 s2)
    __syncthreads();
    float* red = sW;                 // [16][64] s1, then [16][64] s2
    *(float4*)&red[r * 64 + js]        = make_float4(s1[0], s1[1], s1[2], s1[3]);
    *(float4*)&red[1024 + r * 64 + js] = make_float4(s2[0], s2[1], s2[2], s2[3]);
    __syncthreads();
    if (tid < 128) {
        int base = (tid < 64) ? tid : (1024 + tid - 64);
        float v = 0.f;
#pragma unroll
        for (int rr = 0; rr < 16; ++rr) v += red[base + rr * 64];
        P[(long)blockIdx.x * 128 + tid] = v;
    }
}

// ---------------- GEMM3: t3 = silu(BN2(h2)) @ Wl, in-block BN3 row ----------
__global__ void __launch_bounds__(256) gemm3_kernel(
        const float* __restrict__ h2, const float* __restrict__ mr2,
        const float* __restrict__ g, const float* __restrict__ be,
        const float* __restrict__ Wl,
        float* __restrict__ t3, float* __restrict__ P) {
    __shared__ float sW[COUT * COUT]; // 16 KiB (reused as stat scratch)
    __shared__ float sr[NT * COUT];   // 16 KiB
    int tid = threadIdx.x;
    int nbase = blockIdx.x * NT;
    for (int i = tid * 4; i < COUT * COUT; i += 1024)
        *(float4*)&sW[i] = *(const float4*)&Wl[i];
    for (int i = tid * 4; i < NT * COUT; i += 1024) {
        int node = nbase + (i >> 6);
        int j = i & 63;
        float4 v = make_float4(0.f, 0.f, 0.f, 0.f);
        if (node < N_NODES) {
            v = *(const float4*)&h2[(long)node * COUT + j];
            float4 mn = *(const float4*)&mr2[j];
            float4 rq = *(const float4*)&mr2[COUT + j];
            float4 gg = *(const float4*)&g[j];
            float4 bb = *(const float4*)&be[j];
            v.x = (v.x - mn.x) * rq.x * gg.x + bb.x;
            v.y = (v.y - mn.y) * rq.y * gg.y + bb.y;
            v.z = (v.z - mn.z) * rq.z * gg.z + bb.z;
            v.w = (v.w - mn.w) * rq.w * gg.w + bb.w;
            v.x = v.x / (1.f + __expf(-v.x));
            v.y = v.y / (1.f + __expf(-v.y));
            v.z = v.z / (1.f + __expf(-v.z));
            v.w = v.w / (1.f + __expf(-v.w));
        }
        *(float4*)&sr[i] = v;
    }
    __syncthreads();
    int js = (tid & 15) * 4;
    int r  = tid >> 4;
    float acc[4][4];
#pragma unroll
    for (int i = 0; i < 4; ++i) { acc[i][0]=0.f; acc[i][1]=0.f; acc[i][2]=0.f; acc[i][3]=0.f; }
#pragma unroll 4
    for (int k = 0; k < COUT; ++k) {
        float4 w = *(float4*)&sW[k * COUT + js];
#pragma unroll
        for (int i = 0; i < 4; ++i) {
            float a = sr[(r * 4 + i) * COUT + k];
            acc[i][0] = fmaf(a, w.x, acc[i][0]);
            acc[i][1] = fmaf(a, w.y, acc[i][1]);
            acc[i][2] = fmaf(a, w.z, acc[i][2]);
            acc[i][3] = fmaf(a, w.w, acc[i][3]);
        }
    }
    float s1[4] = {0,0,0,0}, s2[4] = {0,0,0,0};
#pragma unroll
    for (int i = 0; i < 4; ++i) {
        int node = nbase + r * 4 + i;
        if (node < N_NODES) {
            *(float4*)&t3[(long)node * COUT + js] =
                make_float4(acc[i][0], acc[i][1], acc[i][2], acc[i][3]);
#pragma unroll
            for (int jj = 0; jj < 4; ++jj) {
                s1[jj] += acc[i][jj];
                s2[jj] += acc[i][jj] * acc[i][jj];
            }
        }
    }
    __syncthreads();
    float* red = sW;                 // [16][64] s1, then [16][64] s2
    *(float4*)&red[r * 64 + js]        = make_float4(s1[0], s1[1], s1[2], s1[3]);
    *(float4*)&red[1024 + r * 64 + js] = make_float4(s2[0], s2[1], s2[2], s2[3]);
    __syncthreads();
    if (tid < 128) {
        int base = (tid < 64) ? tid : (1024 + tid - 64);
        float v = 0.f;
#pragma unroll
        for (int rr = 0; rr < 16; ++rr) v += red[base + rr * 64];
        P[(long)blockIdx.x * 128 + tid] = v;
    }
}

// ---------------- final: out = silu(BN3(t3)), float4 ------------------------
__global__ void final_kernel(const float* __restrict__ t3, const float* __restrict__ mr3,
                             const float* __restrict__ g, const float* __restrict__ be,
                             float* __restrict__ out) {
    long i = ((long)blockIdx.x * blockDim.x + threadIdx.x) * 4;
    int j = (int)(i & 63);
    float4 v = *(const float4*)&t3[i];
    float4 mn = *(const float4*)&mr3[j];
    float4 rq = *(const float4*)&mr3[COUT + j];
    float4 gg = *(const float4*)&g[j];
    float4 bb = *(const float4*)&be[j];
    v.x = (v.x - mn.x) * rq.x * gg.x + bb.x;
    v.y = (v.y - mn.y) * rq.y * gg.y + bb.y;
    v.z = (v.z - mn.z) * rq.z * gg.z + bb.z;
    v.w = (v.w - mn.w) * rq.w * gg.w + bb.w;
    v.x = v.x / (1.f + __expf(-v.x));
    v.y = v.y / (1.f + __expf(-v.y));
    v.z = v.z / (1.f + __expf(-v.z));
    v.w = v.w / (1.f + __expf(-v.w));
    *(float4*)&out[i] = v;
}

extern "C" void kernel_launch(void* const* d_in, const int* in_sizes, int n_in,
                              void* d_out, int out_size, void* d_ws, size_t ws_size,
                              hipStream_t stream) {
    const float* x   = (const float*)d_in[0];
    const int*   ei  = (const int*)d_in[1];
    const float* ea  = (const float*)d_in[2];
    const float* W1  = (const float*)d_in[4];
    const float* b1  = (const float*)d_in[5];
    const float* gm  = (const float*)d_in[6];
    const float* bm  = (const float*)d_in[7];
    const float* W2  = (const float*)d_in[8];
    const float* b2  = (const float*)d_in[9];
    const float* g1  = (const float*)d_in[10];
    const float* be1 = (const float*)d_in[11];
    const float* Wl  = (const float*)d_in[12];
    const float* g2  = (const float*)d_in[13];
    const float* be2 = (const float*)d_in[14];
    float* out = (float*)d_out;

    // workspace layout (floats):
    //   h0[N*64] | t1[N*128] | h2[N*64] | Sfin[512] | Q[16384] | cnt[N] |
    //   tickets[4] | pad | es[N*CAP int2]
    // stat partials alias dead regions: P1->h2, P2->h0, P3->t1
    float* h0   = (float*)d_ws;
    float* t1   = h0 + (long)N_NODES * CIN;
    float* h2   = t1 + (long)N_NODES * CHID;
    float* t3   = h0;
    float* Sfin = h2 + (long)N_NODES * COUT;
    float* Q    = Sfin + 512;
    int*   cnt  = (int*)(Q + RBLK * 256);
    int*   tickets = cnt + N_NODES;
    long   es_off = ((long)(N_NODES * CIN) + (long)N_NODES * CHID + (long)N_NODES * COUT
                     + 512 + RBLK * 256 + N_NODES + 4 + 255) & ~255L;
    int2*  es   = (int2*)((float*)d_ws + es_off);
    float* P1 = h2;
    float* P2 = h0;
    float* P3 = t1;

    const float invN = 1.f / N_NODES;

    hipMemsetAsync(cnt, 0, ((size_t)N_NODES + 4) * sizeof(int), stream);

    bucket_kernel<<<(E_EDGES + 255) / 256, 256, 0, stream>>>(ei, cnt, es);
    gather_kernel<<<(N_NODES * 64 + 255) / 256, 256, 0, stream>>>(x, ea, es, cnt, h0);

    // P is one row per GEMM block now: totrows = NB for all three stages
    const int rpA = (NB + RBLK - 1) / RBLK;   // 25

    gemm1_kernel<<<NB, 256, 0, stream>>>(h0, W1, b1, t1, P1);
    reduce_slab_kernel<<<RBLK, 256, 0, stream>>>(P1, NB, rpA, Q, Sfin, CHID, invN, tickets + 0);
    gemm2_kernel<<<NB, 256, 0, stream>>>(t1, Sfin, gm, bm, W2, b2, h2, P2);
    reduce_slab_kernel<<<RBLK, 128, 0, stream>>>(P2, NB, rpA, Q, Sfin + 256, COUT, invN, tickets + 1);
    gemm3_kernel<<<NB, 256, 0, stream>>>(h2, Sfin + 256, g1, be1, Wl, t3, P3);
    reduce_slab_kernel<<<RBLK, 128, 0, stream>>>(P3, NB, rpA, Q, Sfin + 384, COUT, invN, tickets + 2);
    final_kernel<<<(N_NODES * COUT / 4) / 256, 256, 0, stream>>>(t3, Sfin + 384, g2, be2, out);
}

// Round 11
// 368.741 us; speedup vs baseline: 1.2736x; 1.0325x over previous
//
#include <hip/hip_runtime.h>

#define N_NODES 100000
#define E_EDGES 1600000
#define CIN 64
#define CHID 128
#define COUT 64
#define NT 64                         // nodes per GEMM block
#define NB ((N_NODES + NT - 1) / NT)  // 1563
#define RBLK 64                       // slab blocks for stat reduce
#define CAP 128                       // bucket capacity per node (max degree << CAP)

// ---------------- bucket scatter: counting-sort-free CSR --------------------
__global__ void bucket_kernel(const int* __restrict__ ei, int* __restrict__ cnt,
                              int2* __restrict__ es) {
    int e = blockIdx.x * blockDim.x + threadIdx.x;
    if (e < E_EDGES) {
        int src = ei[e];
        int dst = ei[E_EDGES + e];
        int p = atomicAdd(&cnt[dst], 1);
        if (p < CAP) es[((long)dst << 7) + p] = make_int2(e, src);
    }
}

// ---------------- gather: softmax-aggregate per node, fuse root add --------
// aggr = sum(msg*exp(msg)) / (sum(exp(msg)) + 1e-16); exp(max) cancels vs ref.
// 16-deep main loop: 32 independent row loads in flight per wave.
// ea is streamed-once -> nontemporal (keep L2 for x, which is re-read ~16x).
__global__ void gather_kernel(const float* __restrict__ x,
                              const float* __restrict__ ea,
                              const int2* __restrict__ es,
                              const int* __restrict__ cnt,
                              float* __restrict__ h0) {
    int node = (blockIdx.x * blockDim.x + threadIdx.x) >> 6;
    int lane = threadIdx.x & 63;
    if (node >= N_NODES) return;
    long s = (long)node << 7;
    int n = cnt[node];
    n = n > CAP ? CAP : n;
    float nm = 0.f, dn = 0.f;
    int p = 0;
    for (; p + 16 <= n; p += 16) {
        int2 q[16];
#pragma unroll
        for (int u = 0; u < 16; ++u) q[u] = es[s + p + u];
        float av[16], xv[16];
#pragma unroll
        for (int u = 0; u < 16; ++u)
            av[u] = __builtin_nontemporal_load(ea + (long)q[u].x * CIN + lane);
#pragma unroll
        for (int u = 0; u < 16; ++u) xv[u] = x[(long)q[u].y * CIN + lane];
#pragma unroll
        for (int u = 0; u < 16; ++u) {
            float m = fmaxf(xv[u] + av[u], 0.f) + 1e-7f;
            float ex = __expf(m);
            nm = fmaf(m, ex, nm);
            dn += ex;
        }
    }
    for (; p + 8 <= n; p += 8) {
        int2 q[8];
#pragma unroll
        for (int u = 0; u < 8; ++u) q[u] = es[s + p + u];
        float av[8], xv[8];
#pragma unroll
        for (int u = 0; u < 8; ++u)
            av[u] = __builtin_nontemporal_load(ea + (long)q[u].x * CIN + lane);
#pragma unroll
        for (int u = 0; u < 8; ++u) xv[u] = x[(long)q[u].y * CIN + lane];
#pragma unroll
        for (int u = 0; u < 8; ++u) {
            float m = fmaxf(xv[u] + av[u], 0.f) + 1e-7f;
            float ex = __expf(m);
            nm = fmaf(m, ex, nm);
            dn += ex;
        }
    }
    for (; p + 4 <= n; p += 4) {
        int2 q[4];
#pragma unroll
        for (int u = 0; u < 4; ++u) q[u] = es[s + p + u];
        float av[4], xv[4];
#pragma unroll
        for (int u = 0; u < 4; ++u)
            av[u] = __builtin_nontemporal_load(ea + (long)q[u].x * CIN + lane);
#pragma unroll
        for (int u = 0; u < 4; ++u) xv[u] = x[(long)q[u].y * CIN + lane];
#pragma unroll
        for (int u = 0; u < 4; ++u) {
            float m = fmaxf(xv[u] + av[u], 0.f) + 1e-7f;
            float ex = __expf(m);
            nm = fmaf(m, ex, nm);
            dn += ex;
        }
    }
    for (; p < n; ++p) {
        int2 q = es[s + p];
        float m = fmaxf(x[(long)q.y * CIN + lane] + ea[(long)q.x * CIN + lane], 0.f) + 1e-7f;
        float ex = __expf(m);
        nm = fmaf(m, ex, nm);
        dn += ex;
    }
    h0[(long)node * CIN + lane] = nm / (dn + 1e-16f) + x[(long)node * CIN + lane];
}

// ---------------- slab reduce with last-block-fused finalize ----------------
// P is ONE row per GEMM block (in-block pre-reduced).
__global__ void reduce_slab_kernel(const float* __restrict__ P, int totrows,
                                   int rows_per, float* __restrict__ Q,
                                   float* __restrict__ mr, int C, float invN,
                                   int* __restrict__ ticket) {
    int C2 = blockDim.x;
    int t = threadIdx.x;
    long r0 = (long)blockIdx.x * rows_per;
    long r1 = r0 + rows_per;
    if (r1 > totrows) r1 = totrows;
    {
        float s0 = 0.f, s1 = 0.f, s2 = 0.f, s3 = 0.f;
        long r = r0;
        for (; r + 4 <= r1; r += 4) {
            s0 += P[(r + 0) * C2 + t];
            s1 += P[(r + 1) * C2 + t];
            s2 += P[(r + 2) * C2 + t];
            s3 += P[(r + 3) * C2 + t];
        }
        for (; r < r1; ++r) s0 += P[r * C2 + t];
        Q[(long)blockIdx.x * C2 + t] = (s0 + s1) + (s2 + s3);
    }
    __threadfence();
    __shared__ int lastFlag;
    if (t == 0) lastFlag = (atomicAdd(ticket, 1) == (int)gridDim.x - 1);
    __syncthreads();
    if (!lastFlag) return;
    __threadfence();
    float s0 = 0.f, s1 = 0.f, s2 = 0.f, s3 = 0.f;
    for (int r = 0; r < RBLK; r += 4) {
        s0 += Q[(long)(r + 0) * C2 + t];
        s1 += Q[(long)(r + 1) * C2 + t];
        s2 += Q[(long)(r + 2) * C2 + t];
        s3 += Q[(long)(r + 3) * C2 + t];
    }
    __shared__ float sm[256];
    sm[t] = (s0 + s1) + (s2 + s3);
    __syncthreads();
    if (t < C) {
        float m = sm[t] * invN;
        float v = sm[C + t] * invN - m * m;
        mr[t] = m;
        mr[C + t] = rsqrtf(fmaxf(v, 0.f) + 1e-5f);
    }
}

// ---------------- GEMM1: t1 = h0 @ W1 + b1, in-block BN1 partial row --------
__global__ void __launch_bounds__(256) gemm1_kernel(
        const float* __restrict__ h0, const float* __restrict__ W1,
        const float* __restrict__ b1, float* __restrict__ t1,
        float* __restrict__ P) {
    __shared__ float sW[CIN * CHID];  // 32 KiB (reused as stat scratch)
    __shared__ float sh[NT * CIN];    // 16 KiB
    int tid = threadIdx.x;
    int nbase = blockIdx.x * NT;
    for (int i = tid * 4; i < CIN * CHID; i += 1024)
        *(float4*)&sW[i] = *(const float4*)&W1[i];
    for (int i = tid * 4; i < NT * CIN; i += 1024) {
        int node = nbase + (i >> 6);
        float4 v = make_float4(0.f, 0.f, 0.f, 0.f);
        if (node < N_NODES) v = *(const float4*)&h0[(long)node * CIN + (i & 63)];
        *(float4*)&sh[i] = v;
    }
    __syncthreads();
    int js = (tid & 31) * 4;  // out channels js..js+3
    int r  = tid >> 5;        // node group, nodes r*8 .. r*8+7
    float4 bb = *(const float4*)&b1[js];
    float acc[8][4];
#pragma unroll
    for (int i = 0; i < 8; ++i) { acc[i][0]=bb.x; acc[i][1]=bb.y; acc[i][2]=bb.z; acc[i][3]=bb.w; }
#pragma unroll 4
    for (int k = 0; k < CIN; ++k) {
        float4 w = *(float4*)&sW[k * CHID + js];
#pragma unroll
        for (int i = 0; i < 8; ++i) {
            float a = sh[(r * 8 + i) * CIN + k];
            acc[i][0] = fmaf(a, w.x, acc[i][0]);
            acc[i][1] = fmaf(a, w.y, acc[i][1]);
            acc[i][2] = fmaf(a, w.z, acc[i][2]);
            acc[i][3] = fmaf(a, w.w, acc[i][3]);
        }
    }
    float s1[4] = {0,0,0,0}, s2[4] = {0,0,0,0};
#pragma unroll
    for (int i = 0; i < 8; ++i) {
        int node = nbase + r * 8 + i;
        if (node < N_NODES) {
            *(float4*)&t1[(long)node * CHID + js] =
                make_float4(acc[i][0], acc[i][1], acc[i][2], acc[i][3]);
#pragma unroll
            for (int jj = 0; jj < 4; ++jj) {
                s1[jj] += acc[i][jj];
                s2[jj] += acc[i][jj] * acc[i][jj];
            }
        }
    }
    // in-block stat reduction: 8 r-groups -> one row of 256 (128 s1 | 128 s2)
    __syncthreads();                 // all sW reads done; safe to reuse
    float* red = sW;                 // [8][128] s1, then [8][128] s2
    *(float4*)&red[r * 128 + js]        = make_float4(s1[0], s1[1], s1[2], s1[3]);
    *(float4*)&red[1024 + r * 128 + js] = make_float4(s2[0], s2[1], s2[2], s2[3]);
    __syncthreads();
    {
        int base = (tid < 128) ? tid : (1024 + tid - 128);
        float v = 0.f;
#pragma unroll
        for (int rr = 0; rr < 8; ++rr) v += red[base + rr * 128];
        P[(long)blockIdx.x * 256 + tid] = v;
    }
}

// ---------------- GEMM2: h2 = relu(BN1(t1)) @ W2 + b2, in-block BN2 row -----
__global__ void __launch_bounds__(256) gemm2_kernel(
        const float* __restrict__ t1, const float* __restrict__ mr1,
        const float* __restrict__ g, const float* __restrict__ be,
        const float* __restrict__ W2, const float* __restrict__ b2,
        float* __restrict__ h2, float* __restrict__ P) {
    __shared__ float sW[CHID * COUT]; // 32 KiB (reused as stat scratch)
    __shared__ float sr[NT * CHID];   // 32 KiB
    int tid = threadIdx.x;
    int nbase = blockIdx.x * NT;
    for (int i = tid * 4; i < CHID * COUT; i += 1024)
        *(float4*)&sW[i] = *(const float4*)&W2[i];
    for (int i = tid * 4; i < NT * CHID; i += 1024) {
        int node = nbase + (i >> 7);
        int j = i & 127;
        float4 v = make_float4(0.f, 0.f, 0.f, 0.f);
        if (node < N_NODES) {
            v = *(const float4*)&t1[(long)node * CHID + j];
            float4 mn = *(const float4*)&mr1[j];
            float4 rq = *(const float4*)&mr1[CHID + j];
            float4 gg = *(const float4*)&g[j];
            float4 bb = *(const float4*)&be[j];
            v.x = fmaxf((v.x - mn.x) * rq.x * gg.x + bb.x, 0.f);
            v.y = fmaxf((v.y - mn.y) * rq.y * gg.y + bb.y, 0.f);
            v.z = fmaxf((v.z - mn.z) * rq.z * gg.z + bb.z, 0.f);
            v.w = fmaxf((v.w - mn.w) * rq.w * gg.w + bb.w, 0.f);
        }
        *(float4*)&sr[i] = v;
    }
    __syncthreads();
    int js = (tid & 15) * 4;  // out channels
    int r  = tid >> 4;        // node group, nodes r*4 .. r*4+3
    float4 bb = *(const float4*)&b2[js];
    float acc[4][4];
#pragma unroll
    for (int i = 0; i < 4; ++i) { acc[i][0]=bb.x; acc[i][1]=bb.y; acc[i][2]=bb.z; acc[i][3]=bb.w; }
#pragma unroll 4
    for (int k = 0; k < CHID; ++k) {
        float4 w = *(float4*)&sW[k * COUT + js];
#pragma unroll
        for (int i = 0; i < 4; ++i) {
            float a = sr[(r * 4 + i) * CHID + k];
            acc[i][0] = fmaf(a, w.x, acc[i][0]);
            acc[i][1] = fmaf(a, w.y, acc[i][1]);
            acc[i][2] = fmaf(a, w.z, acc[i][2]);
            acc[i][3] = fmaf(a, w.w, acc[i][3]);
        }
    }
    float s1[4] = {0,0,0,0}, s2[4] = {0,0,0,0};
#pragma unroll
    for (int i = 0; i < 4; ++i) {
        int node = nbase + r * 4 + i;
        if (node < N_NODES) {
            *(float4*)&h2[(long)node * COUT + js] =
                make_float4(acc[i][0], acc[i][1], acc[i][2], acc[i][3]);
#pragma unroll
            for (int jj = 0; jj < 4; ++jj) {
                s1[jj] += acc[i][jj];
                s2[jj] += acc[i][jj] * acc[i][jj];
            }
        }
    }
    // in-block stat reduction: 16 r-groups -> one row of 128 (64 s1 | 64 s2)
    __syncthreads();
    float* red = sW;                 // [16][64] s1, then [16][64] s2
    *(float4*)&red[r * 64 + js]        = make_float4(s1[0], s1[1], s1[2], s1[3]);
    *(float4*)&red[1024 + r * 64 + js] = make_float4(s2[0], s2[1], s2[2], s2[3]);
    __syncthreads();
    if (tid < 128) {
        int base = (tid < 64) ? tid : (1024 + tid - 64);
        float v = 0.f;
#pragma unroll
        for (int rr = 0; rr < 16; ++rr) v += red[base + rr * 64];
        P[(long)blockIdx.x * 128 + tid] = v;
    }
}

// ---------------- GEMM3: t3 = silu(BN2(h2)) @ Wl, in-block BN3 row ----------
__global__ void __launch_bounds__(256) gemm3_kernel(
        const float* __restrict__ h2, const float* __restrict__ mr2,
        const float* __restrict__ g, const float* __restrict__ be,
        const float* __restrict__ Wl,
        float* __restrict__ t3, float* __restrict__ P) {
    __shared__ float sW[COUT * COUT]; // 16 KiB (reused as stat scratch)
    __shared__ float sr[NT * COUT];   // 16 KiB
    int tid = threadIdx.x;
    int nbase = blockIdx.x * NT;
    for (int i = tid * 4; i < COUT * COUT; i += 1024)
        *(float4*)&sW[i] = *(const float4*)&Wl[i];
    for (int i = tid * 4; i < NT * COUT; i += 1024) {
        int node = nbase + (i >> 6);
        int j = i & 63;
        float4 v = make_float4(0.f, 0.f, 0.f, 0.f);
        if (node < N_NODES) {
            v = *(const float4*)&h2[(long)node * COUT + j];
            float4 mn = *(const float4*)&mr2[j];
            float4 rq = *(const float4*)&mr2[COUT + j];
            float4 gg = *(const float4*)&g[j];
            float4 bb = *(const float4*)&be[j];
            v.x = (v.x - mn.x) * rq.x * gg.x + bb.x;
            v.y = (v.y - mn.y) * rq.y * gg.y + bb.y;
            v.z = (v.z - mn.z) * rq.z * gg.z + bb.z;
            v.w = (v.w - mn.w) * rq.w * gg.w + bb.w;
            v.x = v.x / (1.f + __expf(-v.x));
            v.y = v.y / (1.f + __expf(-v.y));
            v.z = v.z / (1.f + __expf(-v.z));
            v.w = v.w / (1.f + __expf(-v.w));
        }
        *(float4*)&sr[i] = v;
    }
    __syncthreads();
    int js = (tid & 15) * 4;
    int r  = tid >> 4;
    float acc[4][4];
#pragma unroll
    for (int i = 0; i < 4; ++i) { acc[i][0]=0.f; acc[i][1]=0.f; acc[i][2]=0.f; acc[i][3]=0.f; }
#pragma unroll 4
    for (int k = 0; k < COUT; ++k) {
        float4 w = *(float4*)&sW[k * COUT + js];
#pragma unroll
        for (int i = 0; i < 4; ++i) {
            float a = sr[(r * 4 + i) * COUT + k];
            acc[i][0] = fmaf(a, w.x, acc[i][0]);
            acc[i][1] = fmaf(a, w.y, acc[i][1]);
            acc[i][2] = fmaf(a, w.z, acc[i][2]);
            acc[i][3] = fmaf(a, w.w, acc[i][3]);
        }
    }
    float s1[4] = {0,0,0,0}, s2[4] = {0,0,0,0};
#pragma unroll
    for (int i = 0; i < 4; ++i) {
        int node = nbase + r * 4 + i;
        if (node < N_NODES) {
            *(float4*)&t3[(long)node * COUT + js] =
                make_float4(acc[i][0], acc[i][1], acc[i][2], acc[i][3]);
#pragma unroll
            for (int jj = 0; jj < 4; ++jj) {
                s1[jj] += acc[i][jj];
                s2[jj] += acc[i][jj] * acc[i][jj];
            }
        }
    }
    __syncthreads();
    float* red = sW;                 // [16][64] s1, then [16][64] s2
    *(float4*)&red[r * 64 + js]        = make_float4(s1[0], s1[1], s1[2], s1[3]);
    *(float4*)&red[1024 + r * 64 + js] = make_float4(s2[0], s2[1], s2[2], s2[3]);
    __syncthreads();
    if (tid < 128) {
        int base = (tid < 64) ? tid : (1024 + tid - 64);
        float v = 0.f;
#pragma unroll
        for (int rr = 0; rr < 16; ++rr) v += red[base + rr * 64];
        P[(long)blockIdx.x * 128 + tid] = v;
    }
}

// ---------------- final: out = silu(BN3(t3)), float4 ------------------------
__global__ void final_kernel(const float* __restrict__ t3, const float* __restrict__ mr3,
                             const float* __restrict__ g, const float* __restrict__ be,
                             float* __restrict__ out) {
    long i = ((long)blockIdx.x * blockDim.x + threadIdx.x) * 4;
    int j = (int)(i & 63);
    float4 v = *(const float4*)&t3[i];
    float4 mn = *(const float4*)&mr3[j];
    float4 rq = *(const float4*)&mr3[COUT + j];
    float4 gg = *(const float4*)&g[j];
    float4 bb = *(const float4*)&be[j];
    v.x = (v.x - mn.x) * rq.x * gg.x + bb.x;
    v.y = (v.y - mn.y) * rq.y * gg.y + bb.y;
    v.z = (v.z - mn.z) * rq.z * gg.z + bb.z;
    v.w = (v.w - mn.w) * rq.w * gg.w + bb.w;
    v.x = v.x / (1.f + __expf(-v.x));
    v.y = v.y / (1.f + __expf(-v.y));
    v.z = v.z / (1.f + __expf(-v.z));
    v.w = v.w / (1.f + __expf(-v.w));
    *(float4*)&out[i] = v;
}

extern "C" void kernel_launch(void* const* d_in, const int* in_sizes, int n_in,
                              void* d_out, int out_size, void* d_ws, size_t ws_size,
                              hipStream_t stream) {
    const float* x   = (const float*)d_in[0];
    const int*   ei  = (const int*)d_in[1];
    const float* ea  = (const float*)d_in[2];
    const float* W1  = (const float*)d_in[4];
    const float* b1  = (const float*)d_in[5];
    const float* gm  = (const float*)d_in[6];
    const float* bm  = (const float*)d_in[7];
    const float* W2  = (const float*)d_in[8];
    const float* b2  = (const float*)d_in[9];
    const float* g1  = (const float*)d_in[10];
    const float* be1 = (const float*)d_in[11];
    const float* Wl  = (const float*)d_in[12];
    const float* g2  = (const float*)d_in[13];
    const float* be2 = (const float*)d_in[14];
    float* out = (float*)d_out;

    // workspace layout (floats):
    //   h0[N*64] | t1[N*128] | h2[N*64] | Sfin[512] | Q[16384] | cnt[N] |
    //   tickets[4] | pad | es[N*CAP int2]
    // stat partials alias dead regions: P1->h2, P2->h0, P3->t1
    float* h0   = (float*)d_ws;
    float* t1   = h0 + (long)N_NODES * CIN;
    float* h2   = t1 + (long)N_NODES * CHID;
    float* t3   = h0;
    float* Sfin = h2 + (long)N_NODES * COUT;
    float* Q    = Sfin + 512;
    int*   cnt  = (int*)(Q + RBLK * 256);
    int*   tickets = cnt + N_NODES;
    long   es_off = ((long)(N_NODES * CIN) + (long)N_NODES * CHID + (long)N_NODES * COUT
                     + 512 + RBLK * 256 + N_NODES + 4 + 255) & ~255L;
    int2*  es   = (int2*)((float*)d_ws + es_off);
    float* P1 = h2;
    float* P2 = h0;
    float* P3 = t1;

    const float invN = 1.f / N_NODES;

    hipMemsetAsync(cnt, 0, ((size_t)N_NODES + 4) * sizeof(int), stream);

    bucket_kernel<<<(E_EDGES + 255) / 256, 256, 0, stream>>>(ei, cnt, es);
    gather_kernel<<<(N_NODES * 64 + 255) / 256, 256, 0, stream>>>(x, ea, es, cnt, h0);

    // P is one row per GEMM block: totrows = NB for all three stages
    const int rpA = (NB + RBLK - 1) / RBLK;   // 25

    gemm1_kernel<<<NB, 256, 0, stream>>>(h0, W1, b1, t1, P1);
    reduce_slab_kernel<<<RBLK, 256, 0, stream>>>(P1, NB, rpA, Q, Sfin, CHID, invN, tickets + 0);
    gemm2_kernel<<<NB, 256, 0, stream>>>(t1, Sfin, gm, bm, W2, b2, h2, P2);
    reduce_slab_kernel<<<RBLK, 128, 0, stream>>>(P2, NB, rpA, Q, Sfin + 256, COUT, invN, tickets + 1);
    gemm3_kernel<<<NB, 256, 0, stream>>>(h2, Sfin + 256, g1, be1, Wl, t3, P3);
    reduce_slab_kernel<<<RBLK, 128, 0, stream>>>(P3, NB, rpA, Q, Sfin + 384, COUT, invN, tickets + 2);
    final_kernel<<<(N_NODES * COUT / 4) / 256, 256, 0, stream>>>(t3, Sfin + 384, g2, be2, out);
}